// Round 1
// baseline (316.107 us; speedup 1.0000x reference)
//
#include <hip/hip_runtime.h>
#include <hip/hip_bf16.h>

typedef __attribute__((ext_vector_type(8))) short bf16x8;
typedef __attribute__((ext_vector_type(4))) float f32x4;
typedef __attribute__((ext_vector_type(8))) unsigned short u16x8;

__device__ __forceinline__ unsigned short f2bf(float f) {
  union { float f; unsigned u; } v; v.f = f;
  unsigned r = v.u + 0x7FFFu + ((v.u >> 16) & 1u);
  return (unsigned short)(r >> 16);
}

__global__ void cast_f32_to_bf16(const float* __restrict__ src,
                                 unsigned short* __restrict__ dst, long n) {
  long t = (long)blockIdx.x * blockDim.x + threadIdx.x;
  long stride = (long)gridDim.x * blockDim.x;
  for (long e = t * 8; e < n; e += stride * 8) {
    f32x4 a = *(const f32x4*)(src + e);
    f32x4 b = *(const f32x4*)(src + e + 4);
    u16x8 o;
    o[0] = f2bf(a[0]); o[1] = f2bf(a[1]); o[2] = f2bf(a[2]); o[3] = f2bf(a[3]);
    o[4] = f2bf(b[0]); o[5] = f2bf(b[1]); o[6] = f2bf(b[2]); o[7] = f2bf(b[3]);
    *(u16x8*)(dst + e) = o;
  }
}

// C = op(A @ B^T), A: [M][K] bf16 row-major, B: [N][K] bf16 row-major.
// EPI==0: Cb[m][n] = bf16( relu(acc + bias[n]) * (scale?scale[n]:1) )
// EPI==1: Cf[m][n] = acc + bconst[0]
// Tiles: 128x128, BK=64. 256 threads = 4 waves (2x2 of 64x64 each).
// LDS tiles [128 rows][64 k] bf16, XOR-swizzled on 16B units: slot ^= (row&7).
template <int EPI>
__global__ __launch_bounds__(256, 2)
void gemm_nt_128(const unsigned short* __restrict__ A,
                 const unsigned short* __restrict__ B,
                 float* __restrict__ Cf, unsigned short* __restrict__ Cb,
                 const float* __restrict__ bias, const float* __restrict__ scale,
                 const float* __restrict__ bconst,
                 int M, int N, int K) {
  __shared__ unsigned short As[128 * 64];
  __shared__ unsigned short Bs[128 * 64];

  int nby = N >> 7;
  int nwg = gridDim.x;
  int wg = blockIdx.x;
  if ((nwg & 7) == 0) {              // XCD-aware swizzle (bijective when nwg%8==0)
    int cpx = nwg >> 3;
    wg = (wg & 7) * cpx + (wg >> 3);
  }
  int bm = wg / nby, bn = wg % nby;
  int m0 = bm << 7, n0 = bn << 7;

  int tid = threadIdx.x;
  int w = tid >> 6, lane = tid & 63;
  int wave_m = (w >> 1) << 6;        // 2x2 wave grid over 128x128
  int wave_n = (w & 1) << 6;

  // --- staging addressing (global_load_lds, 16B/lane) ---
  // tile slot s = i*256 + tid ; row = s>>3 = i*32 + (tid>>3) ; slot-in-row = tid&7
  // LDS is linear; the SOURCE k-chunk is pre-swizzled: kc = (tid&7) ^ (row&7)
  int srow = tid >> 3;
  int kc = (tid & 7) ^ (srow & 7);
  const unsigned short* Ag = A + (size_t)(m0 + srow) * K + kc * 8;
  const unsigned short* Bg = B + (size_t)(n0 + srow) * K + kc * 8;
  unsigned short* Al = &As[w << 9];  // wave-uniform base, + i*2048 per load
  unsigned short* Bl = &Bs[w << 9];

  // --- ds_read fragment bases (swizzled read) ---
  int hi = lane >> 4, lo = lane & 15, e7 = lane & 7;
  int a_base[2], b_base[2];
#pragma unroll
  for (int kk = 0; kk < 2; ++kk) {
    int slot = ((kk << 2) + hi) ^ e7;
    a_base[kk] = (wave_m + lo) * 64 + slot * 8;
    b_base[kk] = (wave_n + lo) * 64 + slot * 8;
  }

  f32x4 acc[4][4] = {};

  int ksteps = K >> 6;
  for (int kt = 0; kt < ksteps; ++kt) {
    const unsigned short* Agk = Ag + kt * 64;
    const unsigned short* Bgk = Bg + kt * 64;
#pragma unroll
    for (int i = 0; i < 4; ++i) {
      __builtin_amdgcn_global_load_lds(
          (const __attribute__((address_space(1))) void*)(Agk + (size_t)(i * 32) * K),
          (__attribute__((address_space(3))) void*)(Al + i * 2048), 16, 0, 0);
    }
#pragma unroll
    for (int i = 0; i < 4; ++i) {
      __builtin_amdgcn_global_load_lds(
          (const __attribute__((address_space(1))) void*)(Bgk + (size_t)(i * 32) * K),
          (__attribute__((address_space(3))) void*)(Bl + i * 2048), 16, 0, 0);
    }
    __syncthreads();  // drains vmcnt(0): staged data visible

    bf16x8 afr[4][2], bfr[4][2];
#pragma unroll
    for (int kk = 0; kk < 2; ++kk) {
#pragma unroll
      for (int t2 = 0; t2 < 4; ++t2) {
        afr[t2][kk] = *(const bf16x8*)(&As[a_base[kk] + t2 * 1024]);
        bfr[t2][kk] = *(const bf16x8*)(&Bs[b_base[kk] + t2 * 1024]);
      }
    }
#pragma unroll
    for (int kk = 0; kk < 2; ++kk) {
#pragma unroll
      for (int mt = 0; mt < 4; ++mt) {
#pragma unroll
        for (int nt = 0; nt < 4; ++nt) {
          acc[mt][nt] = __builtin_amdgcn_mfma_f32_16x16x32_bf16(
              afr[mt][kk], bfr[nt][kk], acc[mt][nt], 0, 0, 0);
        }
      }
    }
    __syncthreads();  // compute done before next-tile overwrite
  }

  // --- epilogue ---
  if (EPI == 0) {
    float bi[4], sc[4];
#pragma unroll
    for (int nt = 0; nt < 4; ++nt) {
      int n = n0 + wave_n + nt * 16 + lo;
      bi[nt] = bias ? bias[n] : 0.f;
      sc[nt] = scale ? scale[n] : 1.f;
    }
#pragma unroll
    for (int mt = 0; mt < 4; ++mt) {
#pragma unroll
      for (int r = 0; r < 4; ++r) {
        size_t m = (size_t)(m0 + wave_m + mt * 16 + hi * 4 + r);
        unsigned short* rowp = Cb + m * (size_t)N + (n0 + wave_n + lo);
#pragma unroll
        for (int nt = 0; nt < 4; ++nt) {
          float v = fmaxf(acc[mt][nt][r] + bi[nt], 0.f) * sc[nt];
          rowp[nt * 16] = f2bf(v);
        }
      }
    }
  } else {
    float badd = bconst[0];
#pragma unroll
    for (int mt = 0; mt < 4; ++mt) {
#pragma unroll
      for (int r = 0; r < 4; ++r) {
        size_t m = (size_t)(m0 + wave_m + mt * 16 + hi * 4 + r);
        float* rowp = Cf + m * (size_t)N + (n0 + wave_n + lo);
#pragma unroll
        for (int nt = 0; nt < 4; ++nt) {
          rowp[nt * 16] = acc[mt][nt][r] + badd;
        }
      }
    }
  }
}

extern "C" void kernel_launch(void* const* d_in, const int* in_sizes, int n_in,
                              void* d_out, int out_size, void* d_ws, size_t ws_size,
                              hipStream_t stream) {
  const float* h  = (const float*)d_in[0];  // [4096,1024]
  const float* l  = (const float*)d_in[1];  // [32000,512]
  const float* Wh = (const float*)d_in[2];  // [512,1024]
  const float* bh = (const float*)d_in[3];  // [512]
  const float* Wl = (const float*)d_in[4];  // [512,512]
  const float* bl = (const float*)d_in[5];  // [512]
  const float* w  = (const float*)d_in[6];  // [512]
  const float* b  = (const float*)d_in[7];  // [1]
  float* out = (float*)d_out;               // [4096,32000]

  char* ws = (char*)d_ws;
  unsigned short* hbf   = (unsigned short*)(ws + 0);          //  8,388,608 B
  unsigned short* Whbf  = (unsigned short*)(ws + 8388608);    //  1,048,576 B
  unsigned short* lbf   = (unsigned short*)(ws + 9437184);    // 32,768,000 B
  unsigned short* Wlbf  = (unsigned short*)(ws + 42205184);   //    524,288 B
  unsigned short* hawbf = (unsigned short*)(ws + 42729472);   //  4,194,304 B
  unsigned short* labf  = (unsigned short*)(ws + 46923776);   // 32,768,000 B
  // total ws use: 79,691,776 B

  auto cast = [&](const float* s, unsigned short* d, long n) {
    long blocks = (n / 8 + 255) / 256;
    if (blocks > 2048) blocks = 2048;
    hipLaunchKernelGGL(cast_f32_to_bf16, dim3((unsigned)blocks), dim3(256), 0, stream,
                       s, d, n);
  };
  cast(h,  hbf,  4096L * 1024);
  cast(Wh, Whbf, 512L * 1024);
  cast(l,  lbf,  32000L * 512);
  cast(Wl, Wlbf, 512L * 512);

  // GEMM1: hawbf = relu(h @ Wh^T + bh) * w   [4096,512], K=1024
  gemm_nt_128<0><<<dim3(32 * 4), dim3(256), 0, stream>>>(
      hbf, Whbf, nullptr, hawbf, bh, w, nullptr, 4096, 512, 1024);
  // GEMM2: labf = relu(l @ Wl^T + bl)        [32000,512], K=512
  gemm_nt_128<0><<<dim3(250 * 4), dim3(256), 0, stream>>>(
      lbf, Wlbf, nullptr, labf, bl, nullptr, nullptr, 32000, 512, 512);
  // main: out = hawbf @ labf^T + b           [4096,32000], K=512
  gemm_nt_128<1><<<dim3(32 * 250), dim3(256), 0, stream>>>(
      hawbf, labf, out, nullptr, nullptr, nullptr, b, 4096, 32000, 512);
}

// Round 2
// 298.162 us; speedup vs baseline: 1.0602x; 1.0602x over previous
//
#include <hip/hip_runtime.h>
#include <hip/hip_bf16.h>

typedef __attribute__((ext_vector_type(8))) short bf16x8;
typedef __attribute__((ext_vector_type(4))) float f32x4;
typedef __attribute__((ext_vector_type(8))) unsigned short u16x8;

__device__ __forceinline__ unsigned short f2bf(float f) {
  union { float f; unsigned u; } v; v.f = f;
  unsigned r = v.u + 0x7FFFu + ((v.u >> 16) & 1u);
  return (unsigned short)(r >> 16);
}

__global__ void cast_f32_to_bf16(const float* __restrict__ src,
                                 unsigned short* __restrict__ dst, long n) {
  long t = (long)blockIdx.x * blockDim.x + threadIdx.x;
  long stride = (long)gridDim.x * blockDim.x;
  for (long e = t * 8; e < n; e += stride * 8) {
    f32x4 a = *(const f32x4*)(src + e);
    f32x4 b = *(const f32x4*)(src + e + 4);
    u16x8 o;
    o[0] = f2bf(a[0]); o[1] = f2bf(a[1]); o[2] = f2bf(a[2]); o[3] = f2bf(a[3]);
    o[4] = f2bf(b[0]); o[5] = f2bf(b[1]); o[6] = f2bf(b[2]); o[7] = f2bf(b[3]);
    *(u16x8*)(dst + e) = o;
  }
}

// ---------------------------------------------------------------------------
// 128x128-tile NT GEMM (round-0 proven kernel) — used for the two small GEMMs.
// EPI==0: Cb[m][n] = bf16( relu(acc + bias[n]) * (scale?scale[n]:1) )
template <int EPI>
__global__ __launch_bounds__(256, 2)
void gemm_nt_128(const unsigned short* __restrict__ A,
                 const unsigned short* __restrict__ B,
                 float* __restrict__ Cf, unsigned short* __restrict__ Cb,
                 const float* __restrict__ bias, const float* __restrict__ scale,
                 const float* __restrict__ bconst,
                 int M, int N, int K) {
  __shared__ unsigned short As[128 * 64];
  __shared__ unsigned short Bs[128 * 64];

  int nby = N >> 7;
  int nwg = gridDim.x;
  int wg = blockIdx.x;
  if ((nwg & 7) == 0) {
    int cpx = nwg >> 3;
    wg = (wg & 7) * cpx + (wg >> 3);
  }
  int bm = wg / nby, bn = wg % nby;
  int m0 = bm << 7, n0 = bn << 7;

  int tid = threadIdx.x;
  int w = tid >> 6, lane = tid & 63;
  int wave_m = (w >> 1) << 6;
  int wave_n = (w & 1) << 6;

  int srow = tid >> 3;
  int kc = (tid & 7) ^ (srow & 7);
  const unsigned short* Ag = A + (size_t)(m0 + srow) * K + kc * 8;
  const unsigned short* Bg = B + (size_t)(n0 + srow) * K + kc * 8;
  unsigned short* Al = &As[w << 9];
  unsigned short* Bl = &Bs[w << 9];

  int hi = lane >> 4, lo = lane & 15, e7 = lane & 7;
  int a_base[2], b_base[2];
#pragma unroll
  for (int kk = 0; kk < 2; ++kk) {
    int slot = ((kk << 2) + hi) ^ e7;
    a_base[kk] = (wave_m + lo) * 64 + slot * 8;
    b_base[kk] = (wave_n + lo) * 64 + slot * 8;
  }

  f32x4 acc[4][4] = {};

  int ksteps = K >> 6;
  for (int kt = 0; kt < ksteps; ++kt) {
    const unsigned short* Agk = Ag + kt * 64;
    const unsigned short* Bgk = Bg + kt * 64;
#pragma unroll
    for (int i = 0; i < 4; ++i) {
      __builtin_amdgcn_global_load_lds(
          (const __attribute__((address_space(1))) void*)(Agk + (size_t)(i * 32) * K),
          (__attribute__((address_space(3))) void*)(Al + i * 2048), 16, 0, 0);
    }
#pragma unroll
    for (int i = 0; i < 4; ++i) {
      __builtin_amdgcn_global_load_lds(
          (const __attribute__((address_space(1))) void*)(Bgk + (size_t)(i * 32) * K),
          (__attribute__((address_space(3))) void*)(Bl + i * 2048), 16, 0, 0);
    }
    __syncthreads();

    bf16x8 afr[4][2], bfr[4][2];
#pragma unroll
    for (int kk = 0; kk < 2; ++kk) {
#pragma unroll
      for (int t2 = 0; t2 < 4; ++t2) {
        afr[t2][kk] = *(const bf16x8*)(&As[a_base[kk] + t2 * 1024]);
        bfr[t2][kk] = *(const bf16x8*)(&Bs[b_base[kk] + t2 * 1024]);
      }
    }
#pragma unroll
    for (int kk = 0; kk < 2; ++kk) {
#pragma unroll
      for (int mt = 0; mt < 4; ++mt) {
#pragma unroll
        for (int nt = 0; nt < 4; ++nt) {
          acc[mt][nt] = __builtin_amdgcn_mfma_f32_16x16x32_bf16(
              afr[mt][kk], bfr[nt][kk], acc[mt][nt], 0, 0, 0);
        }
      }
    }
    __syncthreads();
  }

  if (EPI == 0) {
    float bi[4], sc[4];
#pragma unroll
    for (int nt = 0; nt < 4; ++nt) {
      int n = n0 + wave_n + nt * 16 + lo;
      bi[nt] = bias ? bias[n] : 0.f;
      sc[nt] = scale ? scale[n] : 1.f;
    }
#pragma unroll
    for (int mt = 0; mt < 4; ++mt) {
#pragma unroll
      for (int r = 0; r < 4; ++r) {
        size_t m = (size_t)(m0 + wave_m + mt * 16 + hi * 4 + r);
        unsigned short* rowp = Cb + m * (size_t)N + (n0 + wave_n + lo);
#pragma unroll
        for (int nt = 0; nt < 4; ++nt) {
          float v = fmaxf(acc[mt][nt][r] + bi[nt], 0.f) * sc[nt];
          rowp[nt * 16] = f2bf(v);
        }
      }
    }
  } else {
    float badd = bconst[0];
#pragma unroll
    for (int mt = 0; mt < 4; ++mt) {
#pragma unroll
      for (int r = 0; r < 4; ++r) {
        size_t m = (size_t)(m0 + wave_m + mt * 16 + hi * 4 + r);
        float* rowp = Cf + m * (size_t)N + (n0 + wave_n + lo);
#pragma unroll
        for (int nt = 0; nt < 4; ++nt) {
          rowp[nt * 16] = acc[mt][nt][r] + badd;
        }
      }
    }
  }
}

// ---------------------------------------------------------------------------
// 256x256-tile, BK=64, 8-wave (2Mx4N), 8-phase interleaved schedule (T2+T3+T4+T5).
// A: [M][K] bf16, B: [N][K] bf16, C = A@B^T + bconst[0] (fp32 out).
// LDS: 2 bufs x (A 256x64 + B 256x64) bf16 = 128 KiB. 1 block/CU, 2 waves/SIMD.
// Schedule (race-free by construction):
//   iter j: phases 1-4 read buf0 (K-step 2j'), phases 5-8 read buf1.
//   ph1: stage B(next for buf1), ph2: stage A(next for buf1)  [buf1's old data
//        was last read at prev iter's ph8, consumed before ph8's end barrier]
//   ph4: vmcnt(0) + barrier  -> buf1 stage visible for ph5-8 reads
//   ph5: stage B(next for buf0), ph6: stage A(next for buf0)  [buf0 last read ph4]
//   ph8: vmcnt(0) + barrier  -> buf0 stage visible for next iter ph1-4
// Raw s_barrier (no implicit vmcnt drain); counted cover = 2-3 phases per drain.
__global__ __launch_bounds__(512, 2)
void gemm256_nt(const unsigned short* __restrict__ A,
                const unsigned short* __restrict__ B,
                float* __restrict__ Cf,
                const float* __restrict__ bconst,
                int M, int N, int K) {
  __shared__ unsigned short As[2][256 * 64];
  __shared__ unsigned short Bs[2][256 * 64];

  int nby = N >> 8;
  int nwg = gridDim.x;
  int wg = blockIdx.x;
  if ((nwg & 7) == 0) {
    int cpx = nwg >> 3;
    wg = (wg & 7) * cpx + (wg >> 3);
  }
  int bm = wg / nby, bn = wg % nby;
  int m0 = bm << 8, n0 = bn << 8;

  int tid = threadIdx.x;
  int lane = tid & 63;
  int wid = tid >> 6;
  int wm = wid >> 2, wn = wid & 3;
  int lo = lane & 15, hi = lane >> 4;

  // staging: per-thread pre-swizzled global source, linear LDS dest
  int srow = tid >> 3;
  int schunk = (tid & 7) ^ (srow & 7);
  const unsigned short* Asrc = A + (size_t)(m0 + srow) * K + schunk * 8;
  const unsigned short* Bsrc = B + (size_t)(n0 + srow) * K + schunk * 8;
  int ldst = tid * 8;  // element offset; +i*4096 per sub-load (64 rows each)

  // frag read bases (swizzled): chunk = ((kk<<2)+hi) ^ (lo&7)
  int soff[2];
  soff[0] = (hi ^ (lo & 7)) * 8;
  soff[1] = ((4 + hi) ^ (lo & 7)) * 8;
  int sA_row = (wm * 128 + lo) * 64;  // + mt*1024
  int sB_row = (wn * 64 + lo) * 64;   // + nt*1024

  f32x4 acc[8][4] = {};
  bf16x8 afr[4][2], bfr[2][2];

#define STAGE(SRC, LDSB, KT)                                                    \
  {                                                                             \
    _Pragma("unroll") for (int i_ = 0; i_ < 4; ++i_) {                          \
      __builtin_amdgcn_global_load_lds(                                         \
          (const __attribute__((address_space(1))) void*)(                      \
              (SRC) + (size_t)(KT) * 64 + (size_t)(i_ * 64) * K),               \
          (__attribute__((address_space(3))) void*)((LDSB) + i_ * 4096 + ldst), \
          16, 0, 0);                                                            \
    }                                                                           \
  }

#define PHASE(BUF, MH, NH, READA, STAGE_STMT, VM_STMT)                          \
  {                                                                             \
    STAGE_STMT;                                                                 \
    if (READA) {                                                                \
      _Pragma("unroll") for (int i_ = 0; i_ < 4; ++i_)                          \
        _Pragma("unroll") for (int kk_ = 0; kk_ < 2; ++kk_)                     \
          afr[i_][kk_] = *(const bf16x8*)(                                      \
              &As[BUF][sA_row + ((MH) * 4 + i_) * 1024 + soff[kk_]]);           \
    }                                                                           \
    _Pragma("unroll") for (int j_ = 0; j_ < 2; ++j_)                            \
      _Pragma("unroll") for (int kk_ = 0; kk_ < 2; ++kk_)                       \
        bfr[j_][kk_] = *(const bf16x8*)(                                        \
            &Bs[BUF][sB_row + ((NH) * 2 + j_) * 1024 + soff[kk_]]);             \
    __builtin_amdgcn_s_barrier();                                               \
    asm volatile("s_waitcnt lgkmcnt(0)" ::: "memory");                          \
    __builtin_amdgcn_sched_barrier(0);                                          \
    __builtin_amdgcn_s_setprio(1);                                              \
    _Pragma("unroll") for (int i_ = 0; i_ < 4; ++i_)                            \
      _Pragma("unroll") for (int j_ = 0; j_ < 2; ++j_)                          \
        _Pragma("unroll") for (int kk_ = 0; kk_ < 2; ++kk_)                     \
          acc[(MH) * 4 + i_][(NH) * 2 + j_] =                                   \
              __builtin_amdgcn_mfma_f32_16x16x32_bf16(                          \
                  afr[i_][kk_], bfr[j_][kk_],                                   \
                  acc[(MH) * 4 + i_][(NH) * 2 + j_], 0, 0, 0);                  \
    __builtin_amdgcn_s_setprio(0);                                              \
    VM_STMT;                                                                    \
    __builtin_amdgcn_s_barrier();                                               \
  }

  // prologue: stage K-step 0 into buf 0, drain, barrier
  STAGE(Asrc, &As[0][0], 0);
  STAGE(Bsrc, &Bs[0][0], 0);
  asm volatile("s_waitcnt vmcnt(0)" ::: "memory");
  __builtin_amdgcn_s_barrier();

  int KS = K >> 6;
  for (int j = 0; j < KS; j += 2) {
    bool more = (j + 2) < KS;
    // phases 1-4: compute K-step j from buf0; stage K-step j+1 -> buf1
    PHASE(0, 0, 0, true,  { STAGE(Bsrc, &Bs[1][0], j + 1); }, {});
    PHASE(0, 0, 1, false, { STAGE(Asrc, &As[1][0], j + 1); }, {});
    PHASE(0, 1, 0, true,  {}, {});
    PHASE(0, 1, 1, false, {},
          { asm volatile("s_waitcnt vmcnt(0)" ::: "memory"); });
    // phases 5-8: compute K-step j+1 from buf1; stage K-step j+2 -> buf0
    PHASE(1, 0, 0, true,  { if (more) STAGE(Bsrc, &Bs[0][0], j + 2); }, {});
    PHASE(1, 0, 1, false, { if (more) STAGE(Asrc, &As[0][0], j + 2); }, {});
    PHASE(1, 1, 0, true,  {}, {});
    PHASE(1, 1, 1, false, {},
          { asm volatile("s_waitcnt vmcnt(0)" ::: "memory"); });
  }
#undef PHASE
#undef STAGE

  // epilogue: fp32 store with scalar bias
  float badd = bconst[0];
#pragma unroll
  for (int mt = 0; mt < 8; ++mt) {
#pragma unroll
    for (int r = 0; r < 4; ++r) {
      size_t m = (size_t)(m0 + wm * 128 + mt * 16 + hi * 4 + r);
      float* rowp = Cf + m * (size_t)N + (n0 + wn * 64 + lo);
#pragma unroll
      for (int nt = 0; nt < 4; ++nt) {
        rowp[nt * 16] = acc[mt][nt][r] + badd;
      }
    }
  }
}

extern "C" void kernel_launch(void* const* d_in, const int* in_sizes, int n_in,
                              void* d_out, int out_size, void* d_ws, size_t ws_size,
                              hipStream_t stream) {
  const float* h  = (const float*)d_in[0];  // [4096,1024]
  const float* l  = (const float*)d_in[1];  // [32000,512]
  const float* Wh = (const float*)d_in[2];  // [512,1024]
  const float* bh = (const float*)d_in[3];  // [512]
  const float* Wl = (const float*)d_in[4];  // [512,512]
  const float* bl = (const float*)d_in[5];  // [512]
  const float* w  = (const float*)d_in[6];  // [512]
  const float* b  = (const float*)d_in[7];  // [1]
  float* out = (float*)d_out;               // [4096,32000]

  char* ws = (char*)d_ws;
  unsigned short* hbf   = (unsigned short*)(ws + 0);          //  8,388,608 B
  unsigned short* Whbf  = (unsigned short*)(ws + 8388608);    //  1,048,576 B
  unsigned short* lbf   = (unsigned short*)(ws + 9437184);    // 32,768,000 B
  unsigned short* Wlbf  = (unsigned short*)(ws + 42205184);   //    524,288 B
  unsigned short* hawbf = (unsigned short*)(ws + 42729472);   //  4,194,304 B
  unsigned short* labf  = (unsigned short*)(ws + 46923776);   // 32,768,000 B

  auto cast = [&](const float* s, unsigned short* d, long n) {
    long blocks = (n / 8 + 255) / 256;
    if (blocks > 2048) blocks = 2048;
    hipLaunchKernelGGL(cast_f32_to_bf16, dim3((unsigned)blocks), dim3(256), 0, stream,
                       s, d, n);
  };
  cast(h,  hbf,  4096L * 1024);
  cast(Wh, Whbf, 512L * 1024);
  cast(l,  lbf,  32000L * 512);
  cast(Wl, Wlbf, 512L * 512);

  // GEMM1: hawbf = relu(h @ Wh^T + bh) * w   [4096,512], K=1024
  gemm_nt_128<0><<<dim3(32 * 4), dim3(256), 0, stream>>>(
      hbf, Whbf, nullptr, hawbf, bh, w, nullptr, 4096, 512, 1024);
  // GEMM2: labf = relu(l @ Wl^T + bl)        [32000,512], K=512
  gemm_nt_128<0><<<dim3(250 * 4), dim3(256), 0, stream>>>(
      lbf, Wlbf, nullptr, labf, bl, nullptr, nullptr, 32000, 512, 512);
  // main: out = hawbf @ labf^T + b           [4096,32000], K=512  (8-phase 256^2)
  gemm256_nt<<<dim3(16 * 125), dim3(512), 0, stream>>>(
      hawbf, labf, out, b, 4096, 32000, 512);
}